// Round 11
// baseline (4973.018 us; speedup 1.0000x reference)
//
#include <hip/hip_runtime.h>
#include <hip/hip_bf16.h>
#include <stdint.h>

// GRU decoder: B=128, IN=256, H=512, SEQ=1024, fp32 out.
// R17 = R12 (incremental sentinel-poll ring, PASSED, 2956us) + pure
// MFMA-on-arrival. Convoy model (R13/R15/R16 lessons): step period =
// store-drain + poll-RT + chronic retry rounds + producer work; R15/R16
// (coupling / fewer-fatter producers) regressed; R13 regressed via EARLY
// validation (vmcnt(8)) + scalarization. R17 changes ONLY the round body:
// after ballot-validation (still behind the R12-verbatim store-inclusive
// vmcnt(0)), re-issue still-invalid chunks FIRST, then MFMA newly-valid
// chunks while those re-polls fly. The ~48 MFMAs move from after-the-last-
// round into the chronic retry RTs -> each wave publishes earlier ->
// compounds through the convoy. fp32 accumulate order over kc changes
// (harmless at bf16-dominated tolerance). Everything else R12-verbatim:
// sentinel ring (depth 8, bf16 pairs, |h|<=1 -> bit14==0, 0xFFFFFFFF
// sentinel), sc0 sc1 polls, relaxed system-scope publishes, slot-(s+2)
// reset, per-r immediate publish, nontemporal out, ring 1MB at ws offset 0.

constexpr int SEQ = 1024;
constexpr int BATCH = 128;
constexpr int IND = 256;
constexpr int HD = 512;
constexpr int BG = 8;
constexpr int HG = 32;
constexpr int ROWS = BATCH / BG;   // 16
constexpr int NT = 3;              // tiles: r, z, n (16 cols each)
constexpr int RING_D = 8;
constexpr int SLOT_DW = BATCH * HD / 2;                      // 32768 dwords
constexpr size_t RING_BYTES = (size_t)RING_D * SLOT_DW * 4;  // 1 MB

using frag16 = __attribute__((ext_vector_type(8))) short;  // 8 bf16
using f32x4  = __attribute__((ext_vector_type(4))) float;
using u32x4  = __attribute__((ext_vector_type(4))) unsigned;

__device__ __forceinline__ float sigmoid_f(float x) {
    return 1.f / (1.f + __expf(-x));
}
__device__ __forceinline__ float tanh_f(float x) {
    float e = __expf(2.f * x);
    return 1.f - 2.f / (e + 1.f);
}
__device__ __forceinline__ short f2bf(float x) {
    return (short)__bfloat16_as_ushort(__float2bfloat16(x));
}

__global__ __launch_bounds__(64, 1) void gru_kernel(
    const float* __restrict__ x,      // [128, 256]
    const float* __restrict__ w_ih,   // [1536, 256]
    const float* __restrict__ w_hh,   // [1536, 512] fp32 (converted here)
    const float* __restrict__ b_ih,   // [1536]
    const float* __restrict__ b_hh,   // [1536]
    unsigned* __restrict__ ring,      // RING_D * [128, 512] bf16, 0xFF-filled
    float* __restrict__ out)          // [128, 1024, 512] fp32
{
    const int lane = threadIdx.x;
    const int bg = blockIdx.x & 7;
    const int hg = blockIdx.x >> 3;
    const int b0 = bg * ROWS;
    const int c0 = hg * 16;
    const int nlo = lane & 15;
    const int quad = lane >> 4;

    int gcol[NT];
    gcol[0] = c0 + nlo;           // r
    gcol[1] = HD + c0 + nlo;      // z
    gcol[2] = 2 * HD + c0 + nlo;  // n

    // ---- stage w_hh slice -> LDS in fragment order (once) ----
    __shared__ frag16 ldsB[NT * 16 * 64];  // 48 KB
#pragma unroll
    for (int t = 0; t < NT; ++t) {
        for (int kc = 0; kc < 16; ++kc) {
            const float* src = w_hh + (size_t)gcol[t] * HD + kc * 32 + quad * 8;
            float4 v0 = *(const float4*)src;
            float4 v1 = *(const float4*)(src + 4);
            frag16 f;
            f[0] = f2bf(v0.x); f[1] = f2bf(v0.y); f[2] = f2bf(v0.z); f[3] = f2bf(v0.w);
            f[4] = f2bf(v1.x); f[5] = f2bf(v1.y); f[6] = f2bf(v1.z); f[7] = f2bf(v1.w);
            ldsB[(t * 16 + kc) * 64 + lane] = f;
        }
    }

    // ---- gi = x @ w_ih.T + b_ih (+ b_hh folded for r,z) ----
    float gi[NT][4];
    float bhn = b_hh[gcol[2]];
#pragma unroll
    for (int t = 0; t < NT; ++t) {
        float bi = b_ih[gcol[t]] + ((t < 2) ? b_hh[gcol[t]] : 0.f);
#pragma unroll
        for (int r = 0; r < 4; ++r) gi[t][r] = bi;
    }
    for (int r = 0; r < 4; ++r) {
        const float4* xr = (const float4*)(x + (size_t)(b0 + quad * 4 + r) * IND);
        for (int kc = 0; kc < IND / 4; ++kc) {
            float4 xv = xr[kc];
#pragma unroll
            for (int t = 0; t < NT; ++t) {
                float4 wv = ((const float4*)(w_ih + (size_t)gcol[t] * IND))[kc];
                gi[t][r] += xv.x * wv.x + xv.y * wv.y + xv.z * wv.z + xv.w * wv.w;
            }
        }
    }

    // ---- recurrence ----
    // A-fragment source: lane reads bf16 row (b0+nlo), cols kc*32+quad*8..+8
    // of ring slot (s-1)%8. Byte offset in slot: row*1024 + kc*64 + quad*16.
    const size_t arow_byte = (size_t)(b0 + nlo) * (HD * 2) + quad * 16;

    float hreg[4] = {0.f, 0.f, 0.f, 0.f};

    for (int s = 0; s < SEQ; ++s) {
        f32x4 C[NT];
#pragma unroll
        for (int t = 0; t < NT; ++t) C[t] = (f32x4){0.f, 0.f, 0.f, 0.f};

        if (s > 0) {
            const char* lrow =
                (const char*)(ring + ((s - 1) & (RING_D - 1)) * SLOT_DW) + arow_byte;
            u32x4 raw[16];
            // initial issue of all 16 chunks (R12-verbatim position: after
            // the previous step's publish/reset/out stores)
#pragma unroll
            for (int kc = 0; kc < 16; ++kc)
                asm volatile("global_load_dwordx4 %0, %1, off sc0 sc1"
                             : "=v"(raw[kc]) : "v"(lrow + kc * 64) : "memory");
            unsigned vmask = 0u;
            do {
                // round-1 wait drains the 12 stores too (R13 lesson: this
                // drain is the convoy timing anchor — do not exclude it)
                asm volatile("s_waitcnt vmcnt(0)" ::: "memory");
                __builtin_amdgcn_sched_barrier(0);  // validate below the wait
                // ballot validation (R12-verbatim); vmask/newv wave-uniform
                unsigned newv = 0u;
#pragma unroll
                for (int kc = 0; kc < 16; ++kc) {
                    if (!(vmask & (1u << kc))) {
                        // valid bf16 pair: |h|<=1 -> bit14 of each half == 0
                        unsigned orr = raw[kc][0] | raw[kc][1] | raw[kc][2] | raw[kc][3];
                        if (__ballot((orr & 0x40004000u) == 0u) == ~0ull)
                            newv |= (1u << kc);
                    }
                }
                const unsigned still = 0xFFFFu & ~(vmask | newv);
                // re-issue still-invalid FIRST (re-polls fly during MFMA)
#pragma unroll
                for (int kc = 0; kc < 16; ++kc) {
                    if (still & (1u << kc))
                        asm volatile("global_load_dwordx4 %0, %1, off sc0 sc1"
                                     : "=v"(raw[kc]) : "v"(lrow + kc * 64) : "memory");
                }
                // MFMA newly-valid chunks on arrival (hidden under re-poll RT)
#pragma unroll
                for (int kc = 0; kc < 16; ++kc) {
                    if (newv & (1u << kc)) {
                        union { u32x4 u; frag16 f; } cv;
                        cv.u = raw[kc];
#pragma unroll
                        for (int t = 0; t < NT; ++t) {
                            frag16 bfr = ldsB[(t * 16 + kc) * 64 + lane];
                            C[t] = __builtin_amdgcn_mfma_f32_16x16x32_bf16(cv.f, bfr,
                                                                           C[t], 0, 0, 0);
                        }
                    }
                }
                vmask |= newv;
            } while (vmask != 0xFFFFu);
        }

        // gates; publish each hn[r] the moment it's ready (R12-verbatim)
        unsigned* wslot = ring + (s & (RING_D - 1)) * SLOT_DW;
        unsigned* rslot = ring + ((s + 2) & (RING_D - 1)) * SLOT_DW;
        float hn[4];
#pragma unroll
        for (int r = 0; r < 4; ++r) {
            float gr  = gi[0][r] + C[0][r];
            float gz  = gi[1][r] + C[1][r];
            float ghn = C[2][r] + bhn;
            float rr = sigmoid_f(gr);
            float zz = sigmoid_f(gz);
            float nn = tanh_f(gi[2][r] + rr * ghn);
            hn[r] = (1.f - zz) * nn + zz * hreg[r];
            hreg[r] = hn[r];
            unsigned own = (unsigned)(unsigned short)f2bf(hn[r]);
            unsigned other = (unsigned)__shfl_xor((int)own, 1);
            if ((lane & 1) == 0) {
                int row = b0 + quad * 4 + r;
                unsigned idx = (unsigned)(row * HD + (c0 + nlo)) >> 1;
                __hip_atomic_store(wslot + idx, own | (other << 16),
                                   __ATOMIC_RELAXED, __HIP_MEMORY_SCOPE_SYSTEM);
            }
        }
        // reset slot s+2 (restore sentinel for its reuse; R12-verbatim)
#pragma unroll
        for (int r = 0; r < 4; ++r) {
            if ((lane & 1) == 0) {
                int row = b0 + quad * 4 + r;
                unsigned idx = (unsigned)(row * HD + (c0 + nlo)) >> 1;
                __hip_atomic_store(rslot + idx, 0xFFFFFFFFu,
                                   __ATOMIC_RELAXED, __HIP_MEMORY_SCOPE_SYSTEM);
            }
        }
        // out: non-temporal fp32 stream, don't pollute L2/MALL
#pragma unroll
        for (int r = 0; r < 4; ++r) {
            int row = b0 + quad * 4 + r;
            __builtin_nontemporal_store(
                hn[r], out + (size_t)row * (SEQ * HD) + (size_t)s * HD + (c0 + nlo));
        }
    }
}

extern "C" void kernel_launch(void* const* d_in, const int* in_sizes, int n_in,
                              void* d_out, int out_size, void* d_ws, size_t ws_size,
                              hipStream_t stream) {
    (void)in_sizes; (void)n_in; (void)out_size; (void)ws_size;
    const float* x    = (const float*)d_in[0];
    const float* w_ih = (const float*)d_in[1];
    const float* w_hh = (const float*)d_in[2];
    const float* b_ih = (const float*)d_in[3];
    const float* b_hh = (const float*)d_in[4];

    unsigned* ring = (unsigned*)d_ws;  // proven footprint: 1 MB at offset 0
    hipMemsetAsync(ring, 0xFF, RING_BYTES, stream);  // sentinel fill
    gru_kernel<<<BG * HG, 64, 0, stream>>>(x, w_ih, w_hh, b_ih, b_hh, ring,
                                           (float*)d_out);
}

// Round 12
// 2991.876 us; speedup vs baseline: 1.6622x; 1.6622x over previous
//
#include <hip/hip_runtime.h>
#include <hip/hip_bf16.h>
#include <stdint.h>

// GRU decoder: B=128, IN=256, H=512, SEQ=1024, fp32 out.
// R18 = R12 verbatim (session champion, 2956us; 11% over the R6 baseline).
// Design: sentinel-poll dataflow ring. out-of-band sync eliminated entirely -
// producers store h_s as packed bf16 pairs (relaxed system-scope dwords) into
// a 1MB depth-8 ring; each dword SELF-VALIDATES (|h|<=1 -> bf16 bit14==0;
// sentinel 0xFFFFFFFF), so the consumer's validating data load IS the sync
// (one MALL round trip, no producer drain, no flags). Monotone incremental
// polling: retry rounds re-load only still-invalid chunks (the R12 win:
// cut MALL retry traffic ~8x vs full re-load, FETCH 191->86MB, fixing R9).
// Verified-refuted variations (do not revisit): earlier validation /
// store-excluded waits (R13, -81%), paired-wave poll splitting (R15, -28%),
// fewer-fatter producers (R16, -44%), MFMA-on-arrival in the retry loop
// (R17, -68%), XCD-local sc0-only exchange (R10/R11, hangs), phase-tagged
// no-reset ring (R14, hangs). The store-inclusive vmcnt(0) before validation
// is the convoy's phase-locking delay - it is load-bearing.
// Residual: cross-XCD MALL sync floor (~2.9us/step), not a HW roofline
// (HBM 2%, MFMA 2.7%) - all counter-visible levers exhausted.

constexpr int SEQ = 1024;
constexpr int BATCH = 128;
constexpr int IND = 256;
constexpr int HD = 512;
constexpr int BG = 8;
constexpr int HG = 32;
constexpr int ROWS = BATCH / BG;   // 16
constexpr int NT = 3;              // tiles: r, z, n (16 cols each)
constexpr int RING_D = 8;
constexpr int SLOT_DW = BATCH * HD / 2;                      // 32768 dwords
constexpr size_t RING_BYTES = (size_t)RING_D * SLOT_DW * 4;  // 1 MB

using frag16 = __attribute__((ext_vector_type(8))) short;  // 8 bf16
using f32x4  = __attribute__((ext_vector_type(4))) float;
using u32x4  = __attribute__((ext_vector_type(4))) unsigned;

__device__ __forceinline__ float sigmoid_f(float x) {
    return 1.f / (1.f + __expf(-x));
}
__device__ __forceinline__ float tanh_f(float x) {
    float e = __expf(2.f * x);
    return 1.f - 2.f / (e + 1.f);
}
__device__ __forceinline__ short f2bf(float x) {
    return (short)__bfloat16_as_ushort(__float2bfloat16(x));
}

__global__ __launch_bounds__(64, 1) void gru_kernel(
    const float* __restrict__ x,      // [128, 256]
    const float* __restrict__ w_ih,   // [1536, 256]
    const float* __restrict__ w_hh,   // [1536, 512] fp32 (converted here)
    const float* __restrict__ b_ih,   // [1536]
    const float* __restrict__ b_hh,   // [1536]
    unsigned* __restrict__ ring,      // RING_D * [128, 512] bf16, 0xFF-filled
    float* __restrict__ out)          // [128, 1024, 512] fp32
{
    const int lane = threadIdx.x;
    const int bg = blockIdx.x & 7;
    const int hg = blockIdx.x >> 3;
    const int b0 = bg * ROWS;
    const int c0 = hg * 16;
    const int nlo = lane & 15;
    const int quad = lane >> 4;

    int gcol[NT];
    gcol[0] = c0 + nlo;           // r
    gcol[1] = HD + c0 + nlo;      // z
    gcol[2] = 2 * HD + c0 + nlo;  // n

    // ---- stage w_hh slice -> LDS in fragment order (once) ----
    __shared__ frag16 ldsB[NT * 16 * 64];  // 48 KB
#pragma unroll
    for (int t = 0; t < NT; ++t) {
        for (int kc = 0; kc < 16; ++kc) {
            const float* src = w_hh + (size_t)gcol[t] * HD + kc * 32 + quad * 8;
            float4 v0 = *(const float4*)src;
            float4 v1 = *(const float4*)(src + 4);
            frag16 f;
            f[0] = f2bf(v0.x); f[1] = f2bf(v0.y); f[2] = f2bf(v0.z); f[3] = f2bf(v0.w);
            f[4] = f2bf(v1.x); f[5] = f2bf(v1.y); f[6] = f2bf(v1.z); f[7] = f2bf(v1.w);
            ldsB[(t * 16 + kc) * 64 + lane] = f;
        }
    }

    // ---- gi = x @ w_ih.T + b_ih (+ b_hh folded for r,z) ----
    float gi[NT][4];
    float bhn = b_hh[gcol[2]];
#pragma unroll
    for (int t = 0; t < NT; ++t) {
        float bi = b_ih[gcol[t]] + ((t < 2) ? b_hh[gcol[t]] : 0.f);
#pragma unroll
        for (int r = 0; r < 4; ++r) gi[t][r] = bi;
    }
    for (int r = 0; r < 4; ++r) {
        const float4* xr = (const float4*)(x + (size_t)(b0 + quad * 4 + r) * IND);
        for (int kc = 0; kc < IND / 4; ++kc) {
            float4 xv = xr[kc];
#pragma unroll
            for (int t = 0; t < NT; ++t) {
                float4 wv = ((const float4*)(w_ih + (size_t)gcol[t] * IND))[kc];
                gi[t][r] += xv.x * wv.x + xv.y * wv.y + xv.z * wv.z + xv.w * wv.w;
            }
        }
    }

    // ---- recurrence ----
    // A-fragment source: lane reads bf16 row (b0+nlo), cols kc*32+quad*8..+8
    // of ring slot (s-1)%8. Byte offset in slot: row*1024 + kc*64 + quad*16.
    const size_t arow_byte = (size_t)(b0 + nlo) * (HD * 2) + quad * 16;

    float hreg[4] = {0.f, 0.f, 0.f, 0.f};

    for (int s = 0; s < SEQ; ++s) {
        f32x4 C[NT];
#pragma unroll
        for (int t = 0; t < NT; ++t) C[t] = (f32x4){0.f, 0.f, 0.f, 0.f};

        if (s > 0) {
            const char* lrow =
                (const char*)(ring + ((s - 1) & (RING_D - 1)) * SLOT_DW) + arow_byte;
            u32x4 raw[16];
            // monotone incremental poll: re-load only invalid chunks.
            // vmask is lane-uniform (built from ballots) -> uniform branches.
            unsigned vmask = 0u;
            do {
#pragma unroll
                for (int kc = 0; kc < 16; ++kc) {
                    if (!(vmask & (1u << kc))) {
                        asm volatile("global_load_dwordx4 %0, %1, off sc0 sc1"
                                     : "=v"(raw[kc]) : "v"(lrow + kc * 64) : "memory");
                    }
                }
                asm volatile("s_waitcnt vmcnt(0)" ::: "memory");
                __builtin_amdgcn_sched_barrier(0);  // validate below the wait
#pragma unroll
                for (int kc = 0; kc < 16; ++kc) {
                    if (!(vmask & (1u << kc))) {
                        // valid bf16 pair: |h|<=1 -> bit14 of each half == 0
                        unsigned orr = raw[kc][0] | raw[kc][1] | raw[kc][2] | raw[kc][3];
                        if (__ballot((orr & 0x40004000u) == 0u) == ~0ull)
                            vmask |= (1u << kc);
                    }
                }
            } while (vmask != 0xFFFFu);
            // MFMA: loaded dwords ARE the bf16 A-fragments (zero converts)
#pragma unroll
            for (int kc = 0; kc < 16; ++kc) {
                union { u32x4 u; frag16 f; } cv;
                cv.u = raw[kc];
#pragma unroll
                for (int t = 0; t < NT; ++t) {
                    frag16 bfr = ldsB[(t * 16 + kc) * 64 + lane];
                    C[t] = __builtin_amdgcn_mfma_f32_16x16x32_bf16(cv.f, bfr, C[t], 0, 0, 0);
                }
            }
        }

        // gates; publish each hn[r] the moment it's ready
        unsigned* wslot = ring + (s & (RING_D - 1)) * SLOT_DW;
        unsigned* rslot = ring + ((s + 2) & (RING_D - 1)) * SLOT_DW;
        float hn[4];
#pragma unroll
        for (int r = 0; r < 4; ++r) {
            float gr  = gi[0][r] + C[0][r];
            float gz  = gi[1][r] + C[1][r];
            float ghn = C[2][r] + bhn;
            float rr = sigmoid_f(gr);
            float zz = sigmoid_f(gz);
            float nn = tanh_f(gi[2][r] + rr * ghn);
            hn[r] = (1.f - zz) * nn + zz * hreg[r];
            hreg[r] = hn[r];
            unsigned own = (unsigned)(unsigned short)f2bf(hn[r]);
            unsigned other = (unsigned)__shfl_xor((int)own, 1);
            if ((lane & 1) == 0) {
                int row = b0 + quad * 4 + r;
                unsigned idx = (unsigned)(row * HD + (c0 + nlo)) >> 1;
                __hip_atomic_store(wslot + idx, own | (other << 16),
                                   __ATOMIC_RELAXED, __HIP_MEMORY_SCOPE_SYSTEM);
            }
        }
        // reset slot s+2 (restore sentinel for its reuse at step s+7..)
#pragma unroll
        for (int r = 0; r < 4; ++r) {
            if ((lane & 1) == 0) {
                int row = b0 + quad * 4 + r;
                unsigned idx = (unsigned)(row * HD + (c0 + nlo)) >> 1;
                __hip_atomic_store(rslot + idx, 0xFFFFFFFFu,
                                   __ATOMIC_RELAXED, __HIP_MEMORY_SCOPE_SYSTEM);
            }
        }
        // out: non-temporal fp32 stream, don't pollute L2/MALL
#pragma unroll
        for (int r = 0; r < 4; ++r) {
            int row = b0 + quad * 4 + r;
            __builtin_nontemporal_store(
                hn[r], out + (size_t)row * (SEQ * HD) + (size_t)s * HD + (c0 + nlo));
        }
    }
}

extern "C" void kernel_launch(void* const* d_in, const int* in_sizes, int n_in,
                              void* d_out, int out_size, void* d_ws, size_t ws_size,
                              hipStream_t stream) {
    (void)in_sizes; (void)n_in; (void)out_size; (void)ws_size;
    const float* x    = (const float*)d_in[0];
    const float* w_ih = (const float*)d_in[1];
    const float* w_hh = (const float*)d_in[2];
    const float* b_ih = (const float*)d_in[3];
    const float* b_hh = (const float*)d_in[4];

    unsigned* ring = (unsigned*)d_ws;  // proven footprint: 1 MB at offset 0
    hipMemsetAsync(ring, 0xFF, RING_BYTES, stream);  // sentinel fill
    gru_kernel<<<BG * HG, 64, 0, stream>>>(x, w_ih, w_hh, b_ih, b_hh, ring,
                                           (float*)d_out);
}